// Round 9
// baseline (1121.652 us; speedup 1.0000x reference)
//
#include <hip/hip_runtime.h>

#define MIN_NORM 1e-15f
#define EPSV 1e-5f
#define MAXN (1.0f - EPSV)
#define NN 8192
#define DD 128

typedef unsigned short u16;
typedef __bf16 bf16x8 __attribute__((ext_vector_type(8)));
typedef float f32x4 __attribute__((ext_vector_type(4)));

__device__ __forceinline__ float wave_sum(float v) {
#pragma unroll
  for (int off = 32; off > 0; off >>= 1) v += __shfl_xor(v, off, 64);
  return v;
}

__device__ __forceinline__ float artanh_f(float x) {
  x = fminf(fmaxf(x, -1.0f + EPSV), 1.0f - EPSV);
  return 0.5f * (log1pf(x) - log1pf(-x));
}

__device__ __forceinline__ u16 f2bf(float f) {
  unsigned u = __float_as_uint(f);
  unsigned r = (u + 0x7fffu + ((u >> 16) & 1u)) >> 16;
  return (u16)r;
}
__device__ __forceinline__ float bf2f(u16 b) { return __uint_as_float(((unsigned)b) << 16); }

// monotone float<->uint encoding for atomicMax on floats
__device__ __forceinline__ unsigned fenc(float x) {
  unsigned u = __float_as_uint(x);
  return (u & 0x80000000u) ? ~u : (u | 0x80000000u);
}
__device__ __forceinline__ float fdec(unsigned k) {
  unsigned u = (k & 0x80000000u) ? (k & 0x7fffffffu) : ~k;
  return __uint_as_float(u);
}

__device__ __forceinline__ void gload16(const u16* g, u16* l) {
  __builtin_amdgcn_global_load_lds((const __attribute__((address_space(1))) void*)(g),
                                   (__attribute__((address_space(3))) void*)(l), 16, 0, 0);
}

// ---------------------------------------------------------------------------
// HEAD: one dispatch replacing memset + build_wt + prep_bias + rowwise_init +
// cvt_tile (all mutually independent; consumed only by later dispatches).
// Blocks [0,2048): adj fp32 -> tiled+swizzled bf16.  [2048,2176): init (64
// rows/block).  [2176,2240): weight split-bf16 build.  2240: bias prep + zero
// the atomic scratch (rs/cmaxU/csum) -- replaces the hipMemsetAsync.
// ---------------------------------------------------------------------------
__global__ __launch_bounds__(256) void head_k(const float* __restrict__ x,
                                              const float* __restrict__ adj,
                                              const float* __restrict__ W_conv,
                                              const float* __restrict__ b_conv,
                                              u16* __restrict__ adjT,
                                              float* __restrict__ h,
                                              float* __restrict__ res,
                                              u16* __restrict__ hsplit,
                                              float* __restrict__ hnorm,
                                              u16* __restrict__ Wt2,
                                              float* __restrict__ ebuf,
                                              float* __restrict__ ey2,
                                              float* __restrict__ zblk) {
  const int tid = threadIdx.x;
  const int b = blockIdx.x;
  if (b < 2048) {
    // cvt_tile: rows xb*64..+64, k = kg*512..+512
    int xb = b >> 4, kg = b & 15;
    int ch = tid & 63, rs_ = tid >> 6;
#pragma unroll
    for (int rr = 0; rr < 16; rr++) {
      int row = rr * 4 + rs_;
      int gk = kg * 512 + ch * 8;
      const float* s = adj + (size_t)(xb * 64 + row) * NN + gk;
      float4 a = *(const float4*)s;
      float4 bb = *(const float4*)(s + 4);
      ushort4 d0, d1;
      d0.x = f2bf(a.x); d0.y = f2bf(a.y); d0.z = f2bf(a.z); d0.w = f2bf(a.w);
      d1.x = f2bf(bb.x); d1.y = f2bf(bb.y); d1.z = f2bf(bb.z); d1.w = f2bf(bb.w);
      u16* d = adjT + (((size_t)(xb * 128 + (gk >> 6))) << 12) + row * 64 +
               ((((gk >> 3) & 7) ^ (row & 7)) << 3);
      *(ushort4*)d = d0;
      *(ushort4*)(d + 4) = d1;
    }
  } else if (b < 2176) {
    // rowwise_init: 64 rows per block, 16 per wave
    int w4 = tid >> 6, lane = tid & 63;
    int ib = b - 2048;
    for (int rr = 0; rr < 16; rr++) {
      int i = ib * 64 + w4 * 16 + rr;
      const float* xr = x + (size_t)i * DD;
      float a0 = xr[lane], a1 = xr[lane + 64];
      float n = fmaxf(sqrtf(wave_sum(a0 * a0 + a1 * a1)), MIN_NORM);
      float g = tanhf(n) / n;
      float y0 = g * a0, y1 = g * a1;
      float pn = fmaxf(sqrtf(wave_sum(y0 * y0 + y1 * y1)), MIN_NORM);
      float s = pn > MAXN ? MAXN / pn : 1.0f;
      y0 *= s; y1 *= s;
      size_t base = (size_t)i * DD;
      h[base + lane] = y0;   h[base + lane + 64] = y1;
      res[base + lane] = y0; res[base + lane + 64] = y1;
      u16* row = hsplit + (size_t)i * 384;
      u16 h0 = f2bf(y0), h1 = f2bf(y1);
      u16 l0 = f2bf(y0 - bf2f(h0)), l1 = f2bf(y1 - bf2f(h1));
      row[lane] = h0;         row[lane + 64] = h1;
      row[128 + lane] = l0;   row[128 + 64 + lane] = l1;
      row[256 + lane] = h0;   row[256 + 64 + lane] = h1;
      float hn = fmaxf(sqrtf(wave_sum(y0 * y0 + y1 * y1)), MIN_NORM);
      if (lane == 0) hnorm[i] = hn;
    }
  } else if (b < 2240) {
    // build_wt: 1024 elems per block
    int b2 = b - 2176;
#pragma unroll
    for (int e = 0; e < 4; e++) {
      int idx = b2 * 1024 + e * 256 + tid;
      int layer = idx >> 14;
      int n = (idx >> 7) & 127;
      int k = idx & 127;
      float ev = W_conv[idx];
      u16 hi = f2bf(ev);
      u16 lo = f2bf(ev - bf2f(hi));
      u16* base = Wt2 + (size_t)layer * 128 * 384 + (size_t)n * 384;
      base[k] = hi;
      base[128 + k] = hi;
      base[256 + k] = lo;
    }
  } else {
    // prep_bias: wave = layer; then zero atomic scratch
    int layer = tid >> 6, lane = tid & 63;
    const float* bvec = b_conv + layer * DD;
    float b0 = bvec[lane], b1 = bvec[lane + 64];
    float bn = fmaxf(sqrtf(wave_sum(b0 * b0 + b1 * b1)), MIN_NORM);
    float gb = tanhf(bn) / bn;
    float e0 = gb * b0, e1 = gb * b1;
    float en = fmaxf(sqrtf(wave_sum(e0 * e0 + e1 * e1)), MIN_NORM);
    float sb = en > MAXN ? MAXN / en : 1.0f;
    e0 *= sb; e1 *= sb;
    float y2 = wave_sum(e0 * e0 + e1 * e1);
    ebuf[layer * DD + lane] = e0;
    ebuf[layer * DD + lane + 64] = e1;
    if (lane == 0) ey2[layer] = y2;
    if (tid < 192) zblk[tid] = 0.0f;
  }
}

// ---------------------------------------------------------------------------
// Weight GEMM (K=384) + fused rowwise_mid epilogue (round-8, unchanged).
// ---------------------------------------------------------------------------
__global__ __launch_bounds__(256) void wgemm_mid(const u16* __restrict__ A,
                                                 const u16* __restrict__ Bt,
                                                 const float* __restrict__ hnorm,
                                                 const float* __restrict__ eb,
                                                 const float* __restrict__ ey2,
                                                 u16* __restrict__ uT2) {
  __shared__ __align__(16) u16 Ash[3 * 64 * 64];
  __shared__ __align__(16) u16 Bsh[3 * 128 * 64];

  const int tid = threadIdx.x;
  const int lane = tid & 63;
  const int w = tid >> 6;
  const int wm = w >> 1, wn = w & 1;
  const int lrow = lane & 15;
  const int lq = lane >> 4;
  const int m0 = blockIdx.x * 64;
  const int srow = lane >> 3, spc = lane & 7;
  const int K = 384;
  const u16* Ap = A + (size_t)m0 * K;

  f32x4 acc[2][4];
#pragma unroll
  for (int a = 0; a < 2; a++)
#pragma unroll
    for (int b = 0; b < 4; b++)
#pragma unroll
      for (int r = 0; r < 4; r++) acc[a][b][r] = 0.0f;

#define STAGE(bf, kk)                                                           \
  do {                                                                          \
    _Pragma("unroll") for (int ii = 0; ii < 2; ii++) {                          \
      int rw = ((ii * 4 + w) << 3) + srow;                                      \
      gload16(Ap + (size_t)rw * K + (kk) + ((spc ^ (rw & 7)) << 3),             \
              &Ash[(bf) * 4096 + ((ii * 4 + w) << 9)]);                         \
    }                                                                           \
    _Pragma("unroll") for (int ii = 0; ii < 4; ii++) {                          \
      int rw = ((ii * 4 + w) << 3) + srow;                                      \
      gload16(Bt + (size_t)rw * K + (kk) + ((spc ^ (rw & 7)) << 3),             \
              &Bsh[(bf) * 8192 + ((ii * 4 + w) << 9)]);                         \
    }                                                                           \
  } while (0)

#define COMPUTE(bf)                                                             \
  do {                                                                          \
    const int abase = (bf) * 4096, bbase = (bf) * 8192;                         \
    _Pragma("unroll") for (int ks = 0; ks < 2; ks++) {                          \
      const int lc = ks * 4 + lq;                                               \
      bf16x8 af[2], bfr[4];                                                     \
      _Pragma("unroll") for (int ti = 0; ti < 2; ti++) {                        \
        int r = wm * 32 + ti * 16 + lrow;                                       \
        af[ti] = *(const bf16x8*)&Ash[abase + r * 64 + ((lc ^ (r & 7)) << 3)];  \
      }                                                                         \
      _Pragma("unroll") for (int tj = 0; tj < 4; tj++) {                        \
        int n = wn * 64 + tj * 16 + lrow;                                       \
        bfr[tj] = *(const bf16x8*)&Bsh[bbase + n * 64 + ((lc ^ (n & 7)) << 3)]; \
      }                                                                         \
      _Pragma("unroll") for (int ti = 0; ti < 2; ti++)                          \
        _Pragma("unroll") for (int tj = 0; tj < 4; tj++)                        \
          acc[ti][tj] = __builtin_amdgcn_mfma_f32_16x16x32_bf16(af[ti], bfr[tj], acc[ti][tj], 0, 0, 0); \
    }                                                                           \
  } while (0)

  const int nt = 6;
  STAGE(0, 0);
  STAGE(1, 64);
  for (int t = 0; t < nt - 1; t++) {
    asm volatile("s_waitcnt vmcnt(6)" ::: "memory");
    __builtin_amdgcn_s_barrier();
    if (t + 2 < nt) STAGE((t + 2) % 3, (t + 2) * 64);
    COMPUTE(t % 3);
  }
  asm volatile("s_waitcnt vmcnt(0)" ::: "memory");
  __builtin_amdgcn_s_barrier();
  COMPUTE((nt - 1) % 3);
#undef STAGE
#undef COMPUTE

  float ecol[4];
#pragma unroll
  for (int tj = 0; tj < 4; tj++) ecol[tj] = eb[wn * 64 + tj * 16 + lrow];

  float* sred = (float*)Ash;
#pragma unroll
  for (int ti = 0; ti < 2; ti++)
#pragma unroll
    for (int r = 0; r < 4; r++) {
      float p2 = 0.f, pe = 0.f;
#pragma unroll
      for (int tj = 0; tj < 4; tj++) {
        float v = acc[ti][tj][r];
        p2 = fmaf(v, v, p2);
        pe = fmaf(v, ecol[tj], pe);
      }
#pragma unroll
      for (int off = 1; off < 16; off <<= 1) {
        p2 += __shfl_xor(p2, off, 64);
        pe += __shfl_xor(pe, off, 64);
      }
      if (lrow == 0) {
        int row = wm * 32 + ti * 16 + lq * 4 + r;
        sred[row * 4 + wn * 2 + 0] = p2;
        sred[row * 4 + wn * 2 + 1] = pe;
      }
    }
  __syncthreads();

  const float y2v = *ey2;
  u16* tb = uT2 + ((size_t)blockIdx.x << 13);
#pragma unroll
  for (int ti = 0; ti < 2; ti++)
#pragma unroll
    for (int r = 0; r < 4; r++) {
      int row = wm * 32 + ti * 16 + lq * 4 + r;
      float s2 = sred[row * 4 + 0] + sred[row * 4 + 2];
      float se = sred[row * 4 + 1] + sred[row * 4 + 3];
      float xn = hnorm[m0 + row];
      float mn = fmaxf(sqrtf(s2), MIN_NORM);
      float t = tanhf(mn / xn * artanh_f(xn));
      float vs = t / mn;
      float pn = fmaxf(sqrtf(vs * vs * s2), MIN_NORM);
      float sc2 = pn > MAXN ? MAXN / pn : 1.0f;
      float al = vs * sc2;
      float x2 = al * al * s2;
      float xy = al * se;
      float ca = 1.0f + 2.0f * xy + y2v;
      float cb = 1.0f - x2;
      float den = fmaxf(1.0f + 2.0f * xy + x2 * y2v, MIN_NORM);
      float tn2 = ca * ca * x2 + 2.0f * ca * cb * xy + cb * cb * y2v;
      float tn = fmaxf(sqrtf(fmaxf(tn2, 0.0f)) / den, MIN_NORM);
      float st = tn > MAXN ? MAXN / tn : 1.0f;
      float pn2 = fmaxf(tn * st, MIN_NORM);
      float gl = artanh_f(pn2) / pn2;
      float Ar = gl * st * ca * al / den;
      float Br = gl * st * cb / den;
      int c8 = (row >> 3) & 7, k7 = row & 7;
#pragma unroll
      for (int tj = 0; tj < 4; tj++) {
        int n = wn * 64 + tj * 16 + lrow;
        float u = Ar * acc[ti][tj][r] + Br * ecol[tj];
        tb[n * 64 + ((c8 ^ (n & 7)) << 3) + k7] = f2bf(u);
      }
    }
}

// ---------------------------------------------------------------------------
// adj GEMM (K=8192, NO split-K) + FUSED rowwise_post epilogue.
// Each block owns 64 output rows exclusively -> the entire post chain
// (expmap/relu/expmap + residual + h/hsplit/hnorm writes) runs in-register/
// LDS after the K-loop. Eliminates the P partial buffer (128 MB/iter) and
// one dispatch per layer. Counted-vmcnt 3-buffer ring, 128 k-tiles.
// ---------------------------------------------------------------------------
__global__ __launch_bounds__(256, 1) void adjpost(const u16* __restrict__ A,
                                                  const u16* __restrict__ Bt,
                                                  float* __restrict__ h,
                                                  float* __restrict__ res,
                                                  u16* __restrict__ hsplit,
                                                  float* __restrict__ hnorm,
                                                  int addres) {
  __shared__ __align__(16) u16 Ash[3 * 64 * 64];
  __shared__ __align__(16) u16 Bsh[3 * 128 * 64];

  const int tid = threadIdx.x;
  const int lane = tid & 63;
  const int w = tid >> 6;
  const int wm = w >> 1, wn = w & 1;
  const int lrow = lane & 15;
  const int lq = lane >> 4;
  const int m0 = blockIdx.x * 64;
  const int bxK = blockIdx.x * (NN >> 6);

  f32x4 acc[2][4];
#pragma unroll
  for (int a = 0; a < 2; a++)
#pragma unroll
    for (int b = 0; b < 4; b++)
#pragma unroll
      for (int r = 0; r < 4; r++) acc[a][b][r] = 0.0f;

#define STAGE(bf, tkt)                                                          \
  do {                                                                          \
    const u16* at = A + (((size_t)(bxK + (tkt))) << 12) + (lane << 3);          \
    _Pragma("unroll") for (int ii = 0; ii < 2; ii++)                            \
      gload16(at + ((ii * 4 + w) << 9), &Ash[(bf) * 4096 + ((ii * 4 + w) << 9)]); \
    const u16* bt2 = Bt + (((size_t)(tkt)) << 13) + (lane << 3);                \
    _Pragma("unroll") for (int ii = 0; ii < 4; ii++)                            \
      gload16(bt2 + ((ii * 4 + w) << 9), &Bsh[(bf) * 8192 + ((ii * 4 + w) << 9)]); \
  } while (0)

#define COMPUTE(bf)                                                             \
  do {                                                                          \
    const int abase = (bf) * 4096, bbase = (bf) * 8192;                         \
    _Pragma("unroll") for (int ks = 0; ks < 2; ks++) {                          \
      const int lc = ks * 4 + lq;                                               \
      bf16x8 af[2], bfr[4];                                                     \
      _Pragma("unroll") for (int ti = 0; ti < 2; ti++) {                        \
        int r = wm * 32 + ti * 16 + lrow;                                       \
        af[ti] = *(const bf16x8*)&Ash[abase + r * 64 + ((lc ^ (r & 7)) << 3)];  \
      }                                                                         \
      _Pragma("unroll") for (int tj = 0; tj < 4; tj++) {                        \
        int n = wn * 64 + tj * 16 + lrow;                                       \
        bfr[tj] = *(const bf16x8*)&Bsh[bbase + n * 64 + ((lc ^ (n & 7)) << 3)]; \
      }                                                                         \
      _Pragma("unroll") for (int ti = 0; ti < 2; ti++)                          \
        _Pragma("unroll") for (int tj = 0; tj < 4; tj++)                        \
          acc[ti][tj] = __builtin_amdgcn_mfma_f32_16x16x32_bf16(af[ti], bfr[tj], acc[ti][tj], 0, 0, 0); \
    }                                                                           \
  } while (0)

  const int nt = NN >> 6;  // 128
  STAGE(0, 0);
  STAGE(1, 1);
  for (int t = 0; t < nt - 1; t++) {
    asm volatile("s_waitcnt vmcnt(6)" ::: "memory");
    __builtin_amdgcn_s_barrier();
    if (t + 2 < nt) STAGE((t + 2) % 3, t + 2);
    COMPUTE(t % 3);
  }
  asm volatile("s_waitcnt vmcnt(0)" ::: "memory");
  __builtin_amdgcn_s_barrier();
  COMPUTE((nt - 1) % 3);
#undef STAGE
#undef COMPUTE

  // ---- fused post epilogue (sred lives in ring buffer 0; last compute used
  // buffer (nt-1)%3 = 1, so no clash) ----
  float* sred = (float*)Ash;

  // red1: sum m^2 per row (cross-wn via LDS)
#pragma unroll
  for (int ti = 0; ti < 2; ti++)
#pragma unroll
    for (int r = 0; r < 4; r++) {
      float p = 0.f;
#pragma unroll
      for (int tj = 0; tj < 4; tj++) p = fmaf(acc[ti][tj][r], acc[ti][tj][r], p);
#pragma unroll
      for (int off = 1; off < 16; off <<= 1) p += __shfl_xor(p, off, 64);
      if (lrow == 0) {
        int row2 = wm * 32 + ti * 16 + lq * 4 + r;
        sred[row2 * 2 + wn] = p;
      }
    }
  __syncthreads();

  float c2v[2][4];
#pragma unroll
  for (int ti = 0; ti < 2; ti++)
#pragma unroll
    for (int r = 0; r < 4; r++) {
      int row2 = wm * 32 + ti * 16 + lq * 4 + r;
      float rn = sqrtf(sred[row2 * 2 + 0] + sred[row2 * 2 + 1]);
      float n = fmaxf(rn, MIN_NORM);
      float g = tanhf(n) / n;
      float pn = fmaxf(g * rn, MIN_NORM);
      float s = pn > MAXN ? MAXN / pn : 1.0f;
      float c1 = g * s;
      float hn = fmaxf(c1 * rn, MIN_NORM);
      float gl = artanh_f(hn) / hn;
      c2v[ti][r] = gl * c1;
    }

  // u = relu(c2*m) (overwrite acc); red2: sum u^2
#pragma unroll
  for (int ti = 0; ti < 2; ti++)
#pragma unroll
    for (int tj = 0; tj < 4; tj++)
#pragma unroll
      for (int r = 0; r < 4; r++)
        acc[ti][tj][r] = fmaxf(c2v[ti][r] * acc[ti][tj][r], 0.0f);
#pragma unroll
  for (int ti = 0; ti < 2; ti++)
#pragma unroll
    for (int r = 0; r < 4; r++) {
      float p = 0.f;
#pragma unroll
      for (int tj = 0; tj < 4; tj++) p = fmaf(acc[ti][tj][r], acc[ti][tj][r], p);
#pragma unroll
      for (int off = 1; off < 16; off <<= 1) p += __shfl_xor(p, off, 64);
      if (lrow == 0) {
        int row2 = wm * 32 + ti * 16 + lq * 4 + r;
        sred[128 + row2 * 2 + wn] = p;
      }
    }
  __syncthreads();

  float c3v[2][4];
#pragma unroll
  for (int ti = 0; ti < 2; ti++)
#pragma unroll
    for (int r = 0; r < 4; r++) {
      int row2 = wm * 32 + ti * 16 + lq * 4 + r;
      float rn2 = sqrtf(sred[128 + row2 * 2 + 0] + sred[128 + row2 * 2 + 1]);
      float un = fmaxf(rn2, MIN_NORM);
      float ge = tanhf(un) / un;
      float zn = fmaxf(ge * rn2, MIN_NORM);
      float sz = zn > MAXN ? MAXN / zn : 1.0f;
      c3v[ti][r] = ge * sz;
    }

  // z = c3*u (+ residual); red3: ||z_final||; writes
#pragma unroll
  for (int ti = 0; ti < 2; ti++)
#pragma unroll
    for (int tj = 0; tj < 4; tj++)
#pragma unroll
      for (int r = 0; r < 4; r++) {
        int row2 = wm * 32 + ti * 16 + lq * 4 + r;
        int col = wn * 64 + tj * 16 + lrow;
        size_t gi = (size_t)(m0 + row2) * DD + col;
        float z = c3v[ti][r] * acc[ti][tj][r];
        if (addres) {
          z += res[gi];
          res[gi] = z;
        }
        acc[ti][tj][r] = z;
      }
#pragma unroll
  for (int ti = 0; ti < 2; ti++)
#pragma unroll
    for (int r = 0; r < 4; r++) {
      float p = 0.f;
#pragma unroll
      for (int tj = 0; tj < 4; tj++) p = fmaf(acc[ti][tj][r], acc[ti][tj][r], p);
#pragma unroll
      for (int off = 1; off < 16; off <<= 1) p += __shfl_xor(p, off, 64);
      if (lrow == 0) {
        int row2 = wm * 32 + ti * 16 + lq * 4 + r;
        sred[256 + row2 * 2 + wn] = p;
      }
    }
  __syncthreads();

#pragma unroll
  for (int ti = 0; ti < 2; ti++)
#pragma unroll
    for (int tj = 0; tj < 4; tj++)
#pragma unroll
      for (int r = 0; r < 4; r++) {
        int row2 = wm * 32 + ti * 16 + lq * 4 + r;
        int col = wn * 64 + tj * 16 + lrow;
        float z = acc[ti][tj][r];
        h[(size_t)(m0 + row2) * DD + col] = z;
        u16* rowp = hsplit + (size_t)(m0 + row2) * 384;
        u16 hi = f2bf(z);
        u16 lo = f2bf(z - bf2f(hi));
        rowp[col] = hi;
        rowp[128 + col] = lo;
        rowp[256 + col] = hi;
      }
  if (lrow == 0 && wn == 0) {
#pragma unroll
    for (int ti = 0; ti < 2; ti++)
#pragma unroll
      for (int r = 0; r < 4; r++) {
        int row2 = wm * 32 + ti * 16 + lq * 4 + r;
        hnorm[m0 + row2] =
            fmaxf(sqrtf(sred[256 + row2 * 2 + 0] + sred[256 + row2 * 2 + 1]), MIN_NORM);
      }
  }
}

// ---------------------------------------------------------------------------
// TAIL 1: centroid distances (blocks [0,256)) + node scores (blocks [256,384)).
// ---------------------------------------------------------------------------
__global__ __launch_bounds__(256) void cent_scores(const float* __restrict__ h,
                                                   const float* __restrict__ cen,
                                                   float* __restrict__ rs,
                                                   const float* __restrict__ Wm,
                                                   const float* __restrict__ bm,
                                                   float* __restrict__ sc,
                                                   unsigned* __restrict__ cmaxU) {
  int tid = threadIdx.x;
  if (blockIdx.x < 256) {
    __shared__ float cs[64 * 129];
    __shared__ float hs[32 * 128];
    __shared__ float y2s[64];
    int i0 = blockIdx.x * 32;
    for (int idx = tid; idx < 64 * 128; idx += 256) {
      int r = idx >> 7, c = idx & 127;
      cs[r * 129 + c] = cen[idx];
    }
    for (int idx = tid; idx < 32 * 128; idx += 256) hs[idx] = h[(size_t)i0 * 128 + idx];
    __syncthreads();
    if (tid < 64) {
      float s = 0.f;
      for (int k = 0; k < 128; k++) { float v = cs[tid * 129 + k]; s = fmaf(v, v, s); }
      y2s[tid] = s;
    }
    __syncthreads();
    int w = tid >> 6, lane = tid & 63;
    float dsum = 0.f;
    for (int rr = 0; rr < 8; rr++) {
      int r = w * 8 + rr;
      float dot = 0.f, x2 = 0.f;
      for (int k = 0; k < 128; k++) {
        float hk = hs[r * 128 + k];
        dot = fmaf(hk, cs[lane * 129 + k], dot);
        x2 = fmaf(hk, hk, x2);
      }
      float y2 = y2s[lane];
      float al = 1.0f - 2.0f * dot + y2;
      float be = 1.0f - x2;
      float num2 = al * al * x2 + be * be * y2 - 2.0f * al * be * dot;
      float den = fmaxf(1.0f - 2.0f * dot + x2 * y2, MIN_NORM);
      float d = fmaxf(sqrtf(fmaxf(num2, 0.0f)) / den, MIN_NORM);
      dsum += 2.0f * artanh_f(d);
    }
    atomicAdd(&rs[lane], dsum);
  } else {
    int ib = blockIdx.x - 256;
    int w4 = tid >> 6, lane = tid & 63;
    for (int rr = 0; rr < 16; rr++) {
      int i = ib * 64 + w4 * 16 + rr;
      const float* hr = h + (size_t)i * DD;
      float h0 = hr[lane], h1 = hr[lane + 64];
      float pn = fmaxf(sqrtf(wave_sum(h0 * h0 + h1 * h1)), MIN_NORM);
      float gl = artanh_f(pn) / pn;
      float u0 = gl * h0, u1 = gl * h1;
      float p[7];
#pragma unroll
      for (int j = 0; j < 7; j++)
        p[j] = wave_sum(u0 * Wm[j * 128 + lane] + u1 * Wm[j * 128 + lane + 64]);
      float v = p[0];
#pragma unroll
      for (int j = 1; j < 7; j++)
        if (lane == j) v = p[j];
      if (lane < 7) {
        float sv = v + bm[lane];
        sc[(size_t)i * 7 + lane] = sv;
        atomicMax(&cmaxU[lane], fenc(sv));
      }
    }
  }
}

// TAIL 2: per-class exp-sums (blocks [0,32)) + readout finalize (block 32)
__global__ __launch_bounds__(256) void fin_sum(const float* __restrict__ sc,
                                               const unsigned* __restrict__ cmaxU,
                                               float* __restrict__ csum,
                                               const float* __restrict__ rs,
                                               float* __restrict__ out) {
  int tid = threadIdx.x;
  if (blockIdx.x < 32) {
    __shared__ float buf[256][8];
    int i = blockIdx.x * 256 + tid;
    float cm[7];
#pragma unroll
    for (int j = 0; j < 7; j++) cm[j] = fdec(cmaxU[j]);
#pragma unroll
    for (int j = 0; j < 7; j++) buf[tid][j] = expf(sc[i * 7 + j] - cm[j]);
    __syncthreads();
    for (int off = 128; off > 0; off >>= 1) {
      if (tid < off)
#pragma unroll
        for (int j = 0; j < 7; j++) buf[tid][j] += buf[tid + off][j];
      __syncthreads();
    }
    if (tid < 7) atomicAdd(&csum[tid], buf[0][tid]);
  } else {
    if (tid < 64) {
      float r = rs[tid] * (1.0f / 8192.0f);
      float n = fmaxf(sqrtf(wave_sum(r * r)), MIN_NORM);
      float a = artanh_f(n);
      out[7 + NN * 7 + tid] = a * r / n;
      if (tid < 7) out[tid] = 1.0f;
    }
  }
}

__global__ __launch_bounds__(256) void sm_write(const float* __restrict__ sc,
                                                const unsigned* __restrict__ cmaxU,
                                                const float* __restrict__ csum,
                                                float* __restrict__ out) {
  int idx = blockIdx.x * 256 + threadIdx.x;
  if (idx >= NN * 7) return;
  int i = idx / 7, j = idx - i * 7;
  float cm = fdec(cmaxU[j]);
  out[idx] = expf(sc[i * 7 + j] - cm) / csum[j];
}

extern "C" void kernel_launch(void* const* d_in, const int* in_sizes, int n_in,
                              void* d_out, int out_size, void* d_ws, size_t ws_size,
                              hipStream_t stream) {
  const float* x = (const float*)d_in[0];
  const float* adj = (const float*)d_in[1];
  const float* W_conv = (const float*)d_in[3];
  const float* b_conv = (const float*)d_in[4];
  const float* centroids = (const float*)d_in[5];
  const float* W_mlp1 = (const float*)d_in[8];
  const float* b_mlp1 = (const float*)d_in[9];
  float* out = (float*)d_out;

  char* ws = (char*)d_ws;
  size_t off = 0;
  auto alloc = [&](size_t bytes) {
    void* p = ws + off;
    off = (off + bytes + 255) & ~(size_t)255;
    return p;
  };
  float* h = (float*)alloc((size_t)NN * DD * 4);
  float* res = (float*)alloc((size_t)NN * DD * 4);
  u16* hsplit = (u16*)alloc((size_t)NN * 384 * 2);
  u16* uT2 = (u16*)alloc((size_t)DD * NN * 2);
  u16* Wt2 = (u16*)alloc((size_t)4 * 128 * 384 * 2);
  u16* adjT = (u16*)alloc((size_t)NN * NN * 2);
  float* scores = (float*)alloc((size_t)NN * 7 * 4);
  float* hnorm = (float*)alloc((size_t)NN * 4);
  float* ebuf = (float*)alloc(4 * DD * 4);
  float* ey2 = (float*)alloc(4 * 4);
  float* zblk = (float*)alloc(768);  // rs[64] | cmaxU[7] | csum[7]
  float* rs = zblk;
  unsigned* cmaxU = (unsigned*)(zblk + 64);
  float* csum = zblk + 72;
  (void)ws_size; (void)in_sizes; (void)n_in; (void)out_size;

  head_k<<<2241, 256, 0, stream>>>(x, adj, W_conv, b_conv, adjT, h, res, hsplit,
                                   hnorm, Wt2, ebuf, ey2, zblk);
  for (int layer = 0; layer < 4; layer++) {
    wgemm_mid<<<NN / 64, 256, 0, stream>>>(hsplit, Wt2 + (size_t)layer * 128 * 384,
                                           hnorm, ebuf + layer * DD, ey2 + layer, uT2);
    adjpost<<<NN / 64, 256, 0, stream>>>(adjT, uT2, h, res, hsplit, hnorm, (layer & 1));
  }
  cent_scores<<<384, 256, 0, stream>>>(h, centroids, rs, W_mlp1, b_mlp1, scores, cmaxU);
  fin_sum<<<33, 256, 0, stream>>>(scores, cmaxU, csum, rs, out);
  sm_write<<<(NN * 7 + 255) / 256, 256, 0, stream>>>(scores, cmaxU, csum, out + 7);
}